// Round 5
// baseline (373.827 us; speedup 1.0000x reference)
//
#include <hip/hip_runtime.h>
#include <hip/hip_bf16.h>
#include <stdint.h>

// AttentiveFP readout: B=2048 graphs x (48 real + 1 virtual) nodes, D=256, H=8, DH=32, 4 steps.
// Fused per-graph step kernel v5: A (48x256) held in REGISTERS as MFMA fragments (af[8][3]);
// B (=[Wg;Ws]^T) staged in fat 32KB tiles (128 cols x 128 k), double-buffered, with raw
// s_waitcnt vmcnt(0) + s_barrier and stage-after-barrier so stage(f+1) latency hides under
// compute(f). 8 iterations x 24 MFMA. Virtual-row products come from a small batched GEMM
// (HVSV). Attention fully in registers via shfl butterflies (wave w owns heads w, w+4).

#define NEG_SLOPE 0.2f

typedef unsigned short u16;
typedef short s16x8 __attribute__((ext_vector_type(8)));
typedef float f32x4 __attribute__((ext_vector_type(4)));
typedef u16 u16x4 __attribute__((ext_vector_type(4)));

__device__ __forceinline__ u16 f2bf(float f) {
  union { float f; uint32_t u; } v; v.f = f;
  uint32_t r = (v.u + 0x7FFFu + ((v.u >> 16) & 1u)) >> 16;  // RNE
  return (u16)r;
}
__device__ __forceinline__ float bf2f(u16 h) {
  union { uint32_t u; float f; } v; v.u = ((uint32_t)h) << 16;
  return v.f;
}

__device__ __forceinline__ void gload_lds16(const void* g, void* l) {
  __builtin_amdgcn_global_load_lds(
      (const __attribute__((address_space(1))) void*)g,
      (__attribute__((address_space(3))) void*)l, 16, 0, 0);
}

__device__ __forceinline__ float redsum_lr(float v) {
  v += __shfl_xor(v, 1); v += __shfl_xor(v, 2);
  v += __shfl_xor(v, 4); v += __shfl_xor(v, 8);
  return v;
}
__device__ __forceinline__ float redsum_lk(float v) {
  v += __shfl_xor(v, 16); v += __shfl_xor(v, 32);
  return v;
}
__device__ __forceinline__ float redmax_lk(float v) {
  v = fmaxf(v, __shfl_xor(v, 16)); v = fmaxf(v, __shfl_xor(v, 32));
  return v;
}

// ---------------------------------------------------------------------------
// FUSED step: one block (4 waves) per graph.
// ---------------------------------------------------------------------------
__global__ __launch_bounds__(256, 2)
void fused_step(const u16* __restrict__ X, const u16* __restrict__ W2T,
                const float* __restrict__ HVSV,
                const float* __restrict__ asrc, const float* __restrict__ adst,
                u16* __restrict__ GS, u16* __restrict__ Xn) {
  __shared__ u16 ldsB[2][4 * 128 * 32];  // 2 x 32KB: [kc 0..3][128 r][32 k]
  const int tid = threadIdx.x, b = blockIdx.x;
  const int w = tid >> 6, l = tid & 63, lr = l & 15, lk = l >> 4;
  const int sxor = (lr >> 1) & 3;  // read-side slot xor (bank swizzle)
  const u16* Xg = X + (size_t)b * 48 * 256;

  // ---- A fragments in registers: af[kc][mi] (96 VGPR), load-once ----
  s16x8 af[8][3];
#pragma unroll
  for (int kc = 0; kc < 8; ++kc)
#pragma unroll
    for (int mi = 0; mi < 3; ++mi)
      af[kc][mi] = *(const s16x8*)(Xg + (size_t)(mi * 16 + lr) * 256 + kc * 32 + lk * 8);

  // stage tile (nc, kh): 128 B-rows x 128 k-elems = 32KB, pre-swizzled source cols
#define STAGE_B(NC, KH, BUF)                                                   \
  {                                                                            \
    _Pragma("unroll") for (int i = 0; i < 8; ++i) {                            \
      int q = i * 256 + tid;                                                   \
      int kc = q >> 9, rr = (q >> 2) & 127, c4 = q & 3;                        \
      int c4s = c4 ^ ((rr >> 1) & 3);                                          \
      gload_lds16(W2T + ((size_t)(NC)*128 + rr) * 256 + (KH)*128 + kc * 32 +   \
                      c4s * 8,                                                 \
                  &ldsB[BUF][(i * 256 + w * 64) * 8]);                         \
    }                                                                          \
  }

  constexpr int ord[4] = {2, 3, 0, 1};
  STAGE_B(2, 0, 0)  // f=0 tile

  // ---- per-lane attention params + virtual-row values (from HVSV) ----
  float as_[2][2], ed[2], sv_[2][2];
#pragma unroll
  for (int nc = 0; nc < 2; ++nc) {
    const int head = w + nc * 4;
    float p = 0.f;
#pragma unroll
    for (int ni = 0; ni < 2; ++ni) {
      as_[nc][ni] = asrc[head * 32 + ni * 16 + lr];
      p += HVSV[(size_t)b * 512 + head * 32 + ni * 16 + lr] *
           adst[head * 32 + ni * 16 + lr];
      sv_[nc][ni] = HVSV[(size_t)b * 512 + 256 + nc * 128 + w * 32 + ni * 16 + lr];
    }
    ed[nc] = redsum_lr(p);  // e_dst, broadcast within 16-lane group
  }

  u16x4 hb[2][3][2];  // packed h fragments for attention
  f32x4 acc[3][2];

#pragma unroll
  for (int f = 0; f < 8; ++f) {
    const int nc = ord[f >> 1], kh = f & 1;
    // own stage(f) complete (stage(f+1) not yet issued -> vmcnt(0) waits only f)
    asm volatile("s_waitcnt vmcnt(0) lgkmcnt(0)" ::: "memory");
    __builtin_amdgcn_s_barrier();
    if (f < 7) {
      const int f2 = f + 1;
      STAGE_B(ord[f2 >> 1], f2 & 1, f2 & 1)
    }
    if (kh == 0) {
#pragma unroll
      for (int mi = 0; mi < 3; ++mi)
#pragma unroll
        for (int ni = 0; ni < 2; ++ni) acc[mi][ni] = (f32x4){0.f, 0.f, 0.f, 0.f};
    }
    const u16* bufB = ldsB[f & 1];
#pragma unroll
    for (int kc2 = 0; kc2 < 4; ++kc2) {
      s16x8 bfr[2];
#pragma unroll
      for (int ni = 0; ni < 2; ++ni)
        bfr[ni] = *(const s16x8*)&bufB[((kc2 * 128 + w * 32 + ni * 16 + lr) * 4 +
                                        (lk ^ sxor)) * 8];
#pragma unroll
      for (int mi = 0; mi < 3; ++mi)
#pragma unroll
        for (int ni = 0; ni < 2; ++ni)
          acc[mi][ni] = __builtin_amdgcn_mfma_f32_16x16x32_bf16(
              af[kh * 4 + kc2][mi], bfr[ni], acc[mi][ni], 0, 0, 0);
    }
    if (kh == 1) {
      if (nc >= 2) {  // Ws part: relu -> Xn
        if (Xn) {
#pragma unroll
          for (int mi = 0; mi < 3; ++mi)
#pragma unroll
            for (int ni = 0; ni < 2; ++ni)
#pragma unroll
              for (int j = 0; j < 4; ++j)
                Xn[(size_t)(b * 48 + mi * 16 + lk * 4 + j) * 256 + (nc - 2) * 128 +
                   w * 32 + ni * 16 + lr] = f2bf(fmaxf(acc[mi][ni][j], 0.f));
        }
      } else {  // Wg part: pack h for attention
#pragma unroll
        for (int mi = 0; mi < 3; ++mi)
#pragma unroll
          for (int ni = 0; ni < 2; ++ni)
            hb[nc][mi][ni] = (u16x4){f2bf(acc[mi][ni][0]), f2bf(acc[mi][ni][1]),
                                     f2bf(acc[mi][ni][2]), f2bf(acc[mi][ni][3])};
      }
    }
  }
#undef STAGE_B

  // ---- In-register attention (no LDS, no barriers) ----
#pragma unroll
  for (int nc = 0; nc < 2; ++nc) {
    float al[3][4];
    float m = -1e30f;
#pragma unroll
    for (int mi = 0; mi < 3; ++mi)
#pragma unroll
      for (int j = 0; j < 4; ++j) {
        float p = bf2f(hb[nc][mi][0][j]) * as_[nc][0] +
                  bf2f(hb[nc][mi][1][j]) * as_[nc][1];
        p = redsum_lr(p) + ed[nc];          // e = e_src + e_dst
        p = (p > 0.f) ? p : NEG_SLOPE * p;  // leaky_relu
        al[mi][j] = p;
        m = fmaxf(m, p);
      }
    m = redmax_lk(m);
    float s = 0.f;
#pragma unroll
    for (int mi = 0; mi < 3; ++mi)
#pragma unroll
      for (int j = 0; j < 4; ++j) {
        float ex = expf(al[mi][j] - m);
        al[mi][j] = ex; s += ex;
      }
    s = redsum_lk(s);
    float inv = 1.f / s;
#pragma unroll
    for (int ni = 0; ni < 2; ++ni) {
      float mm = 0.f;
#pragma unroll
      for (int mi = 0; mi < 3; ++mi)
#pragma unroll
        for (int j = 0; j < 4; ++j) mm += al[mi][j] * bf2f(hb[nc][mi][ni][j]);
      mm = redsum_lk(mm) * inv;
      if (lk == 0)
        GS[(size_t)b * 512 + nc * 128 + w * 32 + ni * 16 + lr] =
            f2bf(fmaxf(mm + sv_[nc][ni], 0.f));
    }
  }
}

// ---------------------------------------------------------------------------
// Generic bf16 GEMM: C[M,N] = A[M,K=256] * Bt[N,K=256]^T, 128x128, pipelined.
// EPI: 0 = f32 store; 2 = f32 + bias (projection).
// ---------------------------------------------------------------------------
template<int EPI>
__global__ __launch_bounds__(256)
void gemm_bt(const u16* __restrict__ A, int lda,
             const u16* __restrict__ Bt,
             float* __restrict__ Cf, int ldc, const float* __restrict__ bias) {
  __shared__ u16 ldsA[2][2 * 128 * 32];
  __shared__ u16 ldsB[2][2 * 128 * 32];
  const int tid = threadIdx.x;
  const int w = tid >> 6, l = tid & 63;
  const int wr = w >> 1, wc = w & 1;
  const int lr = l & 15, lk = l >> 4;
  const int sxor = (lr >> 1) & 3;
  const int m0 = blockIdx.x * 128, n0 = blockIdx.y * 128;

#define STAGE_AB(KT, BUF)                                                      \
  {                                                                            \
    const u16* Ag = A + (size_t)m0 * lda + (KT)*64;                            \
    const u16* Bg = Bt + (size_t)n0 * 256 + (KT)*64;                           \
    _Pragma("unroll") for (int i = 0; i < 4; ++i) {                            \
      int q = i * 256 + tid;                                                   \
      int h2 = q >> 9, r = (q >> 2) & 127, c4 = q & 3;                         \
      int c4s = c4 ^ ((r >> 1) & 3);                                           \
      gload_lds16(Ag + (size_t)r * lda + h2 * 32 + c4s * 8,                    \
                  &ldsA[BUF][(i * 256 + w * 64) * 8]);                         \
      gload_lds16(Bg + (size_t)r * 256 + h2 * 32 + c4s * 8,                    \
                  &ldsB[BUF][(i * 256 + w * 64) * 8]);                         \
    }                                                                          \
  }

  f32x4 acc[4][4];
#pragma unroll
  for (int i = 0; i < 4; ++i)
#pragma unroll
    for (int j = 0; j < 4; ++j) acc[i][j] = (f32x4){0.f, 0.f, 0.f, 0.f};

  STAGE_AB(0, 0)
#pragma unroll
  for (int kt = 0; kt < 4; ++kt) {
    __syncthreads();
    if (kt < 3) STAGE_AB(kt + 1, (kt + 1) & 1)
    const u16* bA = ldsA[kt & 1];
    const u16* bB = ldsB[kt & 1];
#pragma unroll
    for (int hh = 0; hh < 2; ++hh) {
      s16x8 af[4], bfr[4];
#pragma unroll
      for (int mi = 0; mi < 4; ++mi)
        af[mi] = *(const s16x8*)&bA[(hh * 128 + wr * 64 + mi * 16 + lr) * 32 +
                                    (lk ^ sxor) * 8];
#pragma unroll
      for (int ni = 0; ni < 4; ++ni)
        bfr[ni] = *(const s16x8*)&bB[(hh * 128 + wc * 64 + ni * 16 + lr) * 32 +
                                     (lk ^ sxor) * 8];
#pragma unroll
      for (int mi = 0; mi < 4; ++mi)
#pragma unroll
        for (int ni = 0; ni < 4; ++ni)
          acc[mi][ni] = __builtin_amdgcn_mfma_f32_16x16x32_bf16(af[mi], bfr[ni],
                                                                acc[mi][ni], 0, 0, 0);
    }
  }
#undef STAGE_AB

#pragma unroll
  for (int mi = 0; mi < 4; ++mi) {
#pragma unroll
    for (int ni = 0; ni < 4; ++ni) {
      f32x4 v = acc[mi][ni];
      int r = m0 + wr * 64 + mi * 16 + lk * 4;
      int c = n0 + wc * 64 + ni * 16 + lr;
#pragma unroll
      for (int j = 0; j < 4; ++j) {
        float fv = v[j];
        if (EPI == 0) Cf[(size_t)(r + j) * ldc + c] = fv;
        else          Cf[(size_t)(r + j) * ldc + c] = fv + bias[c];
      }
    }
  }
}

// Merged GRU-gate GEMM: blockIdx.y<6 -> G1 = g0@wx ; else G2 = state@wh. Pipelined.
__global__ __launch_bounds__(256)
void gemm_gates(const u16* __restrict__ GS, const u16* __restrict__ WXT,
                const u16* __restrict__ WHT, float* __restrict__ G1,
                float* __restrict__ G2) {
  __shared__ u16 ldsA[2][2 * 128 * 32];
  __shared__ u16 ldsB[2][2 * 128 * 32];
  const bool second = blockIdx.y >= 6;
  const u16* A = GS + (second ? 256 : 0);
  const u16* Bt = second ? WHT : WXT;
  float* Cf = second ? G2 : G1;
  const int n0 = (second ? blockIdx.y - 6 : blockIdx.y) * 128;
  const int m0 = blockIdx.x * 128;
  const int tid = threadIdx.x;
  const int w = tid >> 6, l = tid & 63;
  const int wr = w >> 1, wc = w & 1;
  const int lr = l & 15, lk = l >> 4;
  const int sxor = (lr >> 1) & 3;

#define STAGE_AB(KT, BUF)                                                      \
  {                                                                            \
    const u16* Ag = A + (size_t)m0 * 512 + (KT)*64;                            \
    const u16* Bg = Bt + (size_t)n0 * 256 + (KT)*64;                           \
    _Pragma("unroll") for (int i = 0; i < 4; ++i) {                            \
      int q = i * 256 + tid;                                                   \
      int h2 = q >> 9, r = (q >> 2) & 127, c4 = q & 3;                         \
      int c4s = c4 ^ ((r >> 1) & 3);                                           \
      gload_lds16(Ag + (size_t)r * 512 + h2 * 32 + c4s * 8,                    \
                  &ldsA[BUF][(i * 256 + w * 64) * 8]);                         \
      gload_lds16(Bg + (size_t)r * 256 + h2 * 32 + c4s * 8,                    \
                  &ldsB[BUF][(i * 256 + w * 64) * 8]);                         \
    }                                                                          \
  }

  f32x4 acc[4][4];
#pragma unroll
  for (int i = 0; i < 4; ++i)
#pragma unroll
    for (int j = 0; j < 4; ++j) acc[i][j] = (f32x4){0.f, 0.f, 0.f, 0.f};

  STAGE_AB(0, 0)
#pragma unroll
  for (int kt = 0; kt < 4; ++kt) {
    __syncthreads();
    if (kt < 3) STAGE_AB(kt + 1, (kt + 1) & 1)
    const u16* bA = ldsA[kt & 1];
    const u16* bB = ldsB[kt & 1];
#pragma unroll
    for (int hh = 0; hh < 2; ++hh) {
      s16x8 af[4], bfr[4];
#pragma unroll
      for (int mi = 0; mi < 4; ++mi)
        af[mi] = *(const s16x8*)&bA[(hh * 128 + wr * 64 + mi * 16 + lr) * 32 +
                                    (lk ^ sxor) * 8];
#pragma unroll
      for (int ni = 0; ni < 4; ++ni)
        bfr[ni] = *(const s16x8*)&bB[(hh * 128 + wc * 64 + ni * 16 + lr) * 32 +
                                     (lk ^ sxor) * 8];
#pragma unroll
      for (int mi = 0; mi < 4; ++mi)
#pragma unroll
        for (int ni = 0; ni < 4; ++ni)
          acc[mi][ni] = __builtin_amdgcn_mfma_f32_16x16x32_bf16(af[mi], bfr[ni],
                                                                acc[mi][ni], 0, 0, 0);
    }
  }
#undef STAGE_AB

#pragma unroll
  for (int mi = 0; mi < 4; ++mi) {
#pragma unroll
    for (int ni = 0; ni < 4; ++ni) {
      f32x4 v = acc[mi][ni];
      int r = m0 + wr * 64 + mi * 16 + lk * 4;
      int c = n0 + wc * 64 + ni * 16 + lr;
#pragma unroll
      for (int j = 0; j < 4; ++j)
        Cf[(size_t)(r + j) * 768 + c] = v[j];
    }
  }
}

// One-shot transpose-convert of all weights: out[N][K] bf16 from in[K][N] f32.
__global__ void tcvt_all(const float* __restrict__ Wg, const float* __restrict__ Ws,
                         const float* __restrict__ wx, const float* __restrict__ wh,
                         const float* __restrict__ pw,
                         u16* __restrict__ W2T, u16* __restrict__ WXT,
                         u16* __restrict__ WHT, u16* __restrict__ PRJ) {
  int idx = blockIdx.x * 256 + threadIdx.x;
  const float* src; u16* dst; int N; int li;
  if (idx < 65536)        { src = Wg; dst = W2T;          N = 256; li = idx; }
  else if (idx < 131072)  { src = Ws; dst = W2T + 65536;  N = 256; li = idx - 65536; }
  else if (idx < 327680)  { src = wx; dst = WXT;          N = 768; li = idx - 131072; }
  else if (idx < 524288)  { src = wh; dst = WHT;          N = 768; li = idx - 327680; }
  else                    { src = pw; dst = PRJ;          N = 256; li = idx - 524288; }
  int n = li >> 8, k = li & 255;
  dst[li] = f2bf(src[(size_t)k * N + n]);
}

// x0 bf16 + virtual sum -> state f32 + GS state half (bf16). float4 loads, 8B stores.
__global__ __launch_bounds__(256)
void prep_x_kernel(const float* __restrict__ nf, u16* __restrict__ X0,
                   float* __restrict__ state, u16* __restrict__ GS) {
  __shared__ f32x4 part[4][64];
  const int b = blockIdx.x, t = threadIdx.x;
  const int c4 = t & 63, sg = t >> 6;
  const f32x4* src = (const f32x4*)(nf + (size_t)b * 48 * 256);
  f32x4 acc = (f32x4){0.f, 0.f, 0.f, 0.f};
  for (int s = sg * 12; s < sg * 12 + 12; ++s) {
    f32x4 v = src[(size_t)s * 64 + c4];
    acc += v;
    u16x4 o = {f2bf(v[0]), f2bf(v[1]), f2bf(v[2]), f2bf(v[3])};
    *(u16x4*)(X0 + ((size_t)b * 48 + s) * 256 + c4 * 4) = o;
  }
  part[sg][c4] = acc;
  __syncthreads();
  if (t < 64) {
    f32x4 r = part[0][t] + part[1][t] + part[2][t] + part[3][t];
#pragma unroll
    for (int j = 0; j < 4; ++j) {
      int d = t * 4 + j;
      state[(size_t)b * 256 + d] = r[j];
      GS[(size_t)b * 512 + 256 + d] = f2bf(r[j]);
    }
  }
}

// GRU elementwise
__global__ void gru_kernel(const float* __restrict__ G1, const float* __restrict__ G2,
                           const float* __restrict__ bx, const float* __restrict__ bh,
                           float* __restrict__ state, u16* __restrict__ GS) {
  const int b = blockIdx.x, d = threadIdx.x;
  const float* g1 = G1 + (size_t)b * 768;
  const float* g2 = G2 + (size_t)b * 768;
  float xz = g1[d] + bx[d], xr = g1[256 + d] + bx[256 + d], xh = g1[512 + d] + bx[512 + d];
  float hz = g2[d] + bh[d], hr = g2[256 + d] + bh[256 + d], hh2 = g2[512 + d] + bh[512 + d];
  float z = 1.f / (1.f + expf(-(xz + hz)));
  float r = 1.f / (1.f + expf(-(xr + hr)));
  float n = tanhf(xh + r * hh2);
  float h0 = state[b * 256 + d];
  float sn = z * h0 + (1.f - z) * n;
  state[b * 256 + d] = sn;
  GS[(size_t)b * 512 + 256 + d] = f2bf(sn);
}

extern "C" void kernel_launch(void* const* d_in, const int* in_sizes, int n_in,
                              void* d_out, int out_size, void* d_ws, size_t ws_size,
                              hipStream_t stream) {
  const float* nf  = (const float*)d_in[0];
  const float* Wg  = (const float*)d_in[2];
  const float* Ws  = (const float*)d_in[3];
  const float* asr = (const float*)d_in[4];
  const float* ads = (const float*)d_in[5];
  const float* wx  = (const float*)d_in[6];
  const float* wh  = (const float*)d_in[7];
  const float* bx  = (const float*)d_in[8];
  const float* bh  = (const float*)d_in[9];
  const float* pw  = (const float*)d_in[10];
  const float* pb  = (const float*)d_in[11];
  float* out = (float*)d_out;

  char* p = (char*)d_ws;
  size_t off = 0;
  auto alloc = [&](size_t bytes) { char* r = p + off; off += (bytes + 255) & ~255ULL; return r; };
  u16* W2T   = (u16*)alloc(512 * 256 * 2);
  u16* WXT   = (u16*)alloc(768 * 256 * 2);
  u16* WHT   = (u16*)alloc(768 * 256 * 2);
  u16* PRJ   = (u16*)alloc(256 * 256 * 2);
  u16* X0    = (u16*)alloc((size_t)98304 * 256 * 2);
  u16* X1    = (u16*)alloc((size_t)98304 * 256 * 2);
  float* HVSV = (float*)alloc((size_t)2048 * 512 * 4);  // [hv | sv] per graph
  float* G1   = (float*)alloc((size_t)2048 * 768 * 4);
  float* G2   = (float*)alloc((size_t)2048 * 768 * 4);
  u16* GS     = (u16*)alloc((size_t)2048 * 512 * 2);    // [g0 | state] bf16
  float* ST   = (float*)alloc((size_t)2048 * 256 * 4);

  tcvt_all<<<2304, 256, 0, stream>>>(Wg, Ws, wx, wh, pw, W2T, WXT, WHT, PRJ);
  prep_x_kernel<<<2048, 256, 0, stream>>>(nf, X0, ST, GS);

  u16* xc = X0; u16* xn = X1;
  for (int t = 0; t < 4; ++t) {
    // virtual row: hv = state@Wg, sv = state@Ws   (M=2048, N=512)
    gemm_bt<0><<<dim3(16, 4), 256, 0, stream>>>(GS + 256, 512, W2T, HVSV, 512, nullptr);
    // fused: h + attention + g0 + xnext
    fused_step<<<2048, 256, 0, stream>>>(xc, W2T, HVSV, asr, ads, GS, (t < 3) ? xn : nullptr);
    // GRU gates (both in one launch)
    gemm_gates<<<dim3(16, 12), 256, 0, stream>>>(GS, WXT, WHT, G1, G2);
    gru_kernel<<<2048, 256, 0, stream>>>(G1, G2, bx, bh, ST, GS);
    u16* tmp = xc; xc = xn; xn = tmp;
  }
  // out = state @ proj_w + proj_b
  gemm_bt<2><<<dim3(16, 2), 256, 0, stream>>>(GS + 256, 512, PRJ, out, 256, pb);
}

// Round 6
// 283.869 us; speedup vs baseline: 1.3169x; 1.3169x over previous
//
#include <hip/hip_runtime.h>
#include <hip/hip_bf16.h>
#include <stdint.h>

// AttentiveFP readout: B=2048 graphs x (48 real + 1 virtual) nodes, D=256, H=8, DH=32, 4 steps.
// Fused step v6: 4 graphs per block (one per wave). Per-wave A (48x256) in registers.
// B pre-packed fragment-major (BP); per 64-col strip: stage 32KB to LDS (linear, coalesced,
// conflict-free), all 4 waves consume it (384 MFMA/stage). Attention is strip-local
// (strip = 2 heads; softmax is per-head over s) and fully in-register -> h never stored.
// Ws strips write relu->Xn directly. Last step runs only the 4 Wg strips.

#define NEG_SLOPE 0.2f

typedef unsigned short u16;
typedef short s16x8 __attribute__((ext_vector_type(8)));
typedef float f32x4 __attribute__((ext_vector_type(4)));
typedef u16 u16x4 __attribute__((ext_vector_type(4)));
typedef u16 u16x8 __attribute__((ext_vector_type(8)));

__device__ __forceinline__ u16 f2bf(float f) {
  union { float f; uint32_t u; } v; v.f = f;
  uint32_t r = (v.u + 0x7FFFu + ((v.u >> 16) & 1u)) >> 16;  // RNE
  return (u16)r;
}
__device__ __forceinline__ float bf2f(u16 h) {
  union { uint32_t u; float f; } v; v.u = ((uint32_t)h) << 16;
  return v.f;
}

__device__ __forceinline__ void gload_lds16(const void* g, void* l) {
  __builtin_amdgcn_global_load_lds(
      (const __attribute__((address_space(1))) void*)g,
      (__attribute__((address_space(3))) void*)l, 16, 0, 0);
}

__device__ __forceinline__ float redsum_lr(float v) {
  v += __shfl_xor(v, 1); v += __shfl_xor(v, 2);
  v += __shfl_xor(v, 4); v += __shfl_xor(v, 8);
  return v;
}
__device__ __forceinline__ float redsum_lk(float v) {
  v += __shfl_xor(v, 16); v += __shfl_xor(v, 32);
  return v;
}
__device__ __forceinline__ float redmax_lk(float v) {
  v = fmaxf(v, __shfl_xor(v, 16)); v = fmaxf(v, __shfl_xor(v, 32));
  return v;
}

// ---------------------------------------------------------------------------
// FUSED step v6: 512 blocks x 256 threads; wave w handles graph blockIdx*4+w.
// ---------------------------------------------------------------------------
__global__ __launch_bounds__(256, 2)
void fused_step(const u16* __restrict__ X, const u16* __restrict__ BP,
                const float* __restrict__ HVSV,
                const float* __restrict__ asrc, const float* __restrict__ adst,
                u16* __restrict__ GS, u16* __restrict__ Xn) {
  __shared__ u16 ldsB[2][16384];  // 2 x 32KB strip buffers (fragment-major)
  const int tid = threadIdx.x;
  const int w = tid >> 6, l = tid & 63, lr = l & 15, lk = l >> 4;
  const int b = blockIdx.x * 4 + w;
  const u16* Xg = X + (size_t)b * 48 * 256;

  // ---- A fragments in registers: af[kc][mi] = X[mi*16+lr][kc*32+lk*8 .. +7] ----
  s16x8 af[8][3];
#pragma unroll
  for (int kc = 0; kc < 8; ++kc)
#pragma unroll
    for (int mi = 0; mi < 3; ++mi)
      af[kc][mi] = *(const s16x8*)(Xg + (size_t)(mi * 16 + lr) * 256 + kc * 32 + lk * 8);

  // strip s = 2048 contiguous 16B chunks of BP; LDS layout == BP layout (linear copy)
#define STAGE(S, BUF)                                                          \
  {                                                                            \
    _Pragma("unroll") for (int i = 0; i < 8; ++i)                              \
        gload_lds16(BP + ((size_t)(S)*2048 + i * 256 + tid) * 8,               \
                    &ldsB[BUF][(i * 256 + w * 64) * 8]);                       \
  }

  const int NS = Xn ? 8 : 4;  // last step: Wg strips only
  STAGE(0, 0)

  // ---- e_dst per head: hv . att_dst (from HVSV), broadcast to all lanes ----
  float ed[8];
#pragma unroll
  for (int g = 0; g < 4; ++g) {
    float p = HVSV[(size_t)b * 512 + g * 64 + l] * adst[g * 64 + l];
    p += __shfl_xor(p, 1); p += __shfl_xor(p, 2); p += __shfl_xor(p, 4);
    p += __shfl_xor(p, 8); p += __shfl_xor(p, 16);
    ed[2 * g] = __shfl(p, 0);
    ed[2 * g + 1] = __shfl(p, 32);
  }

#pragma unroll
  for (int s = 0; s < 8; ++s) {
    if (s < NS) {
      // own stage(s) landed; barrier covers all waves' stage portions
      asm volatile("s_waitcnt vmcnt(0) lgkmcnt(0)" ::: "memory");
      __builtin_amdgcn_s_barrier();
      if (s + 1 < NS) STAGE(s + 1, (s + 1) & 1)

      f32x4 acc[3][4];
#pragma unroll
      for (int mi = 0; mi < 3; ++mi)
#pragma unroll
        for (int ni = 0; ni < 4; ++ni) acc[mi][ni] = (f32x4){0.f, 0.f, 0.f, 0.f};

      const u16* bufB = ldsB[s & 1];
#pragma unroll
      for (int kc = 0; kc < 8; ++kc) {
        s16x8 bfr[4];
#pragma unroll
        for (int ni = 0; ni < 4; ++ni)
          bfr[ni] = *(const s16x8*)&bufB[((kc * 4 + ni) * 64 + l) * 8];
#pragma unroll
        for (int mi = 0; mi < 3; ++mi)
#pragma unroll
          for (int ni = 0; ni < 4; ++ni)
            acc[mi][ni] = __builtin_amdgcn_mfma_f32_16x16x32_bf16(
                af[kc][mi], bfr[ni], acc[mi][ni], 0, 0, 0);
      }

      if (s < 4) {
        // ---- strip-local attention: heads 2s, 2s+1; rows mi*16+lk*4+j ----
        float sv0[4];
#pragma unroll
        for (int ni = 0; ni < 4; ++ni)
          sv0[ni] = HVSV[(size_t)b * 512 + 256 + s * 64 + ni * 16 + lr];
#pragma unroll
        for (int hi = 0; hi < 2; ++hi) {
          const int nb = 2 * hi;
          const float as0 = asrc[(2 * s + hi) * 32 + lr];
          const float as1 = asrc[(2 * s + hi) * 32 + 16 + lr];
          float al[3][4];
          float m = -1e30f;
#pragma unroll
          for (int mi = 0; mi < 3; ++mi)
#pragma unroll
            for (int j = 0; j < 4; ++j) {
              float p = acc[mi][nb][j] * as0 + acc[mi][nb + 1][j] * as1;
              p = redsum_lr(p) + ed[2 * s + hi];   // e = e_src + e_dst
              p = (p > 0.f) ? p : NEG_SLOPE * p;   // leaky_relu
              al[mi][j] = p;
              m = fmaxf(m, p);
            }
          m = redmax_lk(m);  // max over all 48 nodes
          float sm = 0.f;
#pragma unroll
          for (int mi = 0; mi < 3; ++mi)
#pragma unroll
            for (int j = 0; j < 4; ++j) {
              float ex = expf(al[mi][j] - m);
              al[mi][j] = ex; sm += ex;
            }
          sm = redsum_lk(sm);
          const float inv = 1.f / sm;
#pragma unroll
          for (int ni = nb; ni <= nb + 1; ++ni) {
            float mm = 0.f;
#pragma unroll
            for (int mi = 0; mi < 3; ++mi)
#pragma unroll
              for (int j = 0; j < 4; ++j) mm += al[mi][j] * acc[mi][ni][j];
            mm = redsum_lk(mm) * inv;  // msg over 48 nodes
            if (lk == 0)
              GS[(size_t)b * 512 + s * 64 + ni * 16 + lr] =
                  f2bf(fmaxf(mm + sv0[ni], 0.f));  // g0 = relu(msg + sv)
          }
        }
      } else {
        // ---- Ws strip: relu -> Xn ----
#pragma unroll
        for (int mi = 0; mi < 3; ++mi)
#pragma unroll
          for (int ni = 0; ni < 4; ++ni)
#pragma unroll
            for (int j = 0; j < 4; ++j)
              Xn[(size_t)(b * 48 + mi * 16 + lk * 4 + j) * 256 + (s - 4) * 64 +
                 ni * 16 + lr] = f2bf(fmaxf(acc[mi][ni][j], 0.f));
      }
    }
  }
#undef STAGE
}

// ---------------------------------------------------------------------------
// Generic bf16 GEMM: C[M,N] = A[M,K=256] * Bt[N,K=256]^T, 128x128, pipelined.
// EPI: 0 = f32 store; 2 = f32 + bias (projection).
// ---------------------------------------------------------------------------
template<int EPI>
__global__ __launch_bounds__(256)
void gemm_bt(const u16* __restrict__ A, int lda,
             const u16* __restrict__ Bt,
             float* __restrict__ Cf, int ldc, const float* __restrict__ bias) {
  __shared__ u16 ldsA[2][2 * 128 * 32];
  __shared__ u16 ldsB[2][2 * 128 * 32];
  const int tid = threadIdx.x;
  const int w = tid >> 6, l = tid & 63;
  const int wr = w >> 1, wc = w & 1;
  const int lr = l & 15, lk = l >> 4;
  const int sxor = (lr >> 1) & 3;
  const int m0 = blockIdx.x * 128, n0 = blockIdx.y * 128;

#define STAGE_AB(KT, BUF)                                                      \
  {                                                                            \
    const u16* Ag = A + (size_t)m0 * lda + (KT)*64;                            \
    const u16* Bg = Bt + (size_t)n0 * 256 + (KT)*64;                           \
    _Pragma("unroll") for (int i = 0; i < 4; ++i) {                            \
      int q = i * 256 + tid;                                                   \
      int h2 = q >> 9, r = (q >> 2) & 127, c4 = q & 3;                         \
      int c4s = c4 ^ ((r >> 1) & 3);                                           \
      gload_lds16(Ag + (size_t)r * lda + h2 * 32 + c4s * 8,                    \
                  &ldsA[BUF][(i * 256 + w * 64) * 8]);                         \
      gload_lds16(Bg + (size_t)r * 256 + h2 * 32 + c4s * 8,                    \
                  &ldsB[BUF][(i * 256 + w * 64) * 8]);                         \
    }                                                                          \
  }

  f32x4 acc[4][4];
#pragma unroll
  for (int i = 0; i < 4; ++i)
#pragma unroll
    for (int j = 0; j < 4; ++j) acc[i][j] = (f32x4){0.f, 0.f, 0.f, 0.f};

  STAGE_AB(0, 0)
#pragma unroll
  for (int kt = 0; kt < 4; ++kt) {
    __syncthreads();
    if (kt < 3) STAGE_AB(kt + 1, (kt + 1) & 1)
    const u16* bA = ldsA[kt & 1];
    const u16* bB = ldsB[kt & 1];
#pragma unroll
    for (int hh = 0; hh < 2; ++hh) {
      s16x8 af[4], bfr[4];
#pragma unroll
      for (int mi = 0; mi < 4; ++mi)
        af[mi] = *(const s16x8*)&bA[(hh * 128 + wr * 64 + mi * 16 + lr) * 32 +
                                    (lk ^ sxor) * 8];
#pragma unroll
      for (int ni = 0; ni < 4; ++ni)
        bfr[ni] = *(const s16x8*)&bB[(hh * 128 + wc * 64 + ni * 16 + lr) * 32 +
                                     (lk ^ sxor) * 8];
#pragma unroll
      for (int mi = 0; mi < 4; ++mi)
#pragma unroll
        for (int ni = 0; ni < 4; ++ni)
          acc[mi][ni] = __builtin_amdgcn_mfma_f32_16x16x32_bf16(af[mi], bfr[ni],
                                                                acc[mi][ni], 0, 0, 0);
    }
  }
#undef STAGE_AB

#pragma unroll
  for (int mi = 0; mi < 4; ++mi) {
#pragma unroll
    for (int ni = 0; ni < 4; ++ni) {
      f32x4 v = acc[mi][ni];
      int r = m0 + wr * 64 + mi * 16 + lk * 4;
      int c = n0 + wc * 64 + ni * 16 + lr;
#pragma unroll
      for (int j = 0; j < 4; ++j) {
        float fv = v[j];
        if (EPI == 0) Cf[(size_t)(r + j) * ldc + c] = fv;
        else          Cf[(size_t)(r + j) * ldc + c] = fv + bias[c];
      }
    }
  }
}

// Merged GRU-gate GEMM: blockIdx.y<6 -> G1 = g0@wx ; else G2 = state@wh. Pipelined.
__global__ __launch_bounds__(256)
void gemm_gates(const u16* __restrict__ GS, const u16* __restrict__ WXT,
                const u16* __restrict__ WHT, float* __restrict__ G1,
                float* __restrict__ G2) {
  __shared__ u16 ldsA[2][2 * 128 * 32];
  __shared__ u16 ldsB[2][2 * 128 * 32];
  const bool second = blockIdx.y >= 6;
  const u16* A = GS + (second ? 256 : 0);
  const u16* Bt = second ? WHT : WXT;
  float* Cf = second ? G2 : G1;
  const int n0 = (second ? blockIdx.y - 6 : blockIdx.y) * 128;
  const int m0 = blockIdx.x * 128;
  const int tid = threadIdx.x;
  const int w = tid >> 6, l = tid & 63;
  const int wr = w >> 1, wc = w & 1;
  const int lr = l & 15, lk = l >> 4;
  const int sxor = (lr >> 1) & 3;

#define STAGE_AB(KT, BUF)                                                      \
  {                                                                            \
    const u16* Ag = A + (size_t)m0 * 512 + (KT)*64;                            \
    const u16* Bg = Bt + (size_t)n0 * 256 + (KT)*64;                           \
    _Pragma("unroll") for (int i = 0; i < 4; ++i) {                            \
      int q = i * 256 + tid;                                                   \
      int h2 = q >> 9, r = (q >> 2) & 127, c4 = q & 3;                         \
      int c4s = c4 ^ ((r >> 1) & 3);                                           \
      gload_lds16(Ag + (size_t)r * 512 + h2 * 32 + c4s * 8,                    \
                  &ldsA[BUF][(i * 256 + w * 64) * 8]);                         \
      gload_lds16(Bg + (size_t)r * 256 + h2 * 32 + c4s * 8,                    \
                  &ldsB[BUF][(i * 256 + w * 64) * 8]);                         \
    }                                                                          \
  }

  f32x4 acc[4][4];
#pragma unroll
  for (int i = 0; i < 4; ++i)
#pragma unroll
    for (int j = 0; j < 4; ++j) acc[i][j] = (f32x4){0.f, 0.f, 0.f, 0.f};

  STAGE_AB(0, 0)
#pragma unroll
  for (int kt = 0; kt < 4; ++kt) {
    __syncthreads();
    if (kt < 3) STAGE_AB(kt + 1, (kt + 1) & 1)
    const u16* bA = ldsA[kt & 1];
    const u16* bB = ldsB[kt & 1];
#pragma unroll
    for (int hh = 0; hh < 2; ++hh) {
      s16x8 af[4], bfr[4];
#pragma unroll
      for (int mi = 0; mi < 4; ++mi)
        af[mi] = *(const s16x8*)&bA[(hh * 128 + wr * 64 + mi * 16 + lr) * 32 +
                                    (lk ^ sxor) * 8];
#pragma unroll
      for (int ni = 0; ni < 4; ++ni)
        bfr[ni] = *(const s16x8*)&bB[(hh * 128 + wc * 64 + ni * 16 + lr) * 32 +
                                     (lk ^ sxor) * 8];
#pragma unroll
      for (int mi = 0; mi < 4; ++mi)
#pragma unroll
        for (int ni = 0; ni < 4; ++ni)
          acc[mi][ni] = __builtin_amdgcn_mfma_f32_16x16x32_bf16(af[mi], bfr[ni],
                                                                acc[mi][ni], 0, 0, 0);
    }
  }
#undef STAGE_AB

#pragma unroll
  for (int mi = 0; mi < 4; ++mi) {
#pragma unroll
    for (int ni = 0; ni < 4; ++ni) {
      f32x4 v = acc[mi][ni];
      int r = m0 + wr * 64 + mi * 16 + lk * 4;
      int c = n0 + wc * 64 + ni * 16 + lr;
#pragma unroll
      for (int j = 0; j < 4; ++j)
        Cf[(size_t)(r + j) * 768 + c] = v[j];
    }
  }
}

// One-shot transpose-convert of weights: out[N][K] bf16 from in[K][N] f32.
__global__ void tcvt_all(const float* __restrict__ Wg, const float* __restrict__ Ws,
                         const float* __restrict__ wx, const float* __restrict__ wh,
                         const float* __restrict__ pw,
                         u16* __restrict__ W2T, u16* __restrict__ WXT,
                         u16* __restrict__ WHT, u16* __restrict__ PRJ) {
  int idx = blockIdx.x * 256 + threadIdx.x;
  const float* src; u16* dst; int N; int li;
  if (idx < 65536)        { src = Wg; dst = W2T;          N = 256; li = idx; }
  else if (idx < 131072)  { src = Ws; dst = W2T + 65536;  N = 256; li = idx - 65536; }
  else if (idx < 327680)  { src = wx; dst = WXT;          N = 768; li = idx - 131072; }
  else if (idx < 524288)  { src = wh; dst = WHT;          N = 768; li = idx - 327680; }
  else                    { src = pw; dst = PRJ;          N = 256; li = idx - 524288; }
  int n = li >> 8, k = li & 255;
  dst[li] = f2bf(src[(size_t)k * N + n]);
}

// Fragment-major packing of [Wg | Ws] for fused_step.
// chunk c: l=c&63, ni=(c>>6)&3, kc=(c>>8)&7, s=c>>11;
// BP[c][e] = bf16(W[kc*32+(l>>4)*8+e][s*64+ni*16+(l&15)]).
__global__ void tcvt_bp(const float* __restrict__ Wg, const float* __restrict__ Ws,
                        u16* __restrict__ BP) {
  int c = blockIdx.x * 256 + threadIdx.x;  // 16384 chunks
  int l = c & 63, ni = (c >> 6) & 3, kc = (c >> 8) & 7, s = c >> 11;
  int n = s * 64 + ni * 16 + (l & 15);
  int k0 = kc * 32 + (l >> 4) * 8;
  const float* W = (n < 256) ? Wg : Ws;
  int nn = n & 255;
  u16x8 o;
#pragma unroll
  for (int e = 0; e < 8; ++e) o[e] = f2bf(W[(size_t)(k0 + e) * 256 + nn]);
  *(u16x8*)(BP + (size_t)c * 8) = o;
}

// x0 bf16 + virtual sum -> state f32 + GS state half (bf16). float4 loads, 8B stores.
__global__ __launch_bounds__(256)
void prep_x_kernel(const float* __restrict__ nf, u16* __restrict__ X0,
                   float* __restrict__ state, u16* __restrict__ GS) {
  __shared__ f32x4 part[4][64];
  const int b = blockIdx.x, t = threadIdx.x;
  const int c4 = t & 63, sg = t >> 6;
  const f32x4* src = (const f32x4*)(nf + (size_t)b * 48 * 256);
  f32x4 acc = (f32x4){0.f, 0.f, 0.f, 0.f};
  for (int s = sg * 12; s < sg * 12 + 12; ++s) {
    f32x4 v = src[(size_t)s * 64 + c4];
    acc += v;
    u16x4 o = {f2bf(v[0]), f2bf(v[1]), f2bf(v[2]), f2bf(v[3])};
    *(u16x4*)(X0 + ((size_t)b * 48 + s) * 256 + c4 * 4) = o;
  }
  part[sg][c4] = acc;
  __syncthreads();
  if (t < 64) {
    f32x4 r = part[0][t] + part[1][t] + part[2][t] + part[3][t];
#pragma unroll
    for (int j = 0; j < 4; ++j) {
      int d = t * 4 + j;
      state[(size_t)b * 256 + d] = r[j];
      GS[(size_t)b * 512 + 256 + d] = f2bf(r[j]);
    }
  }
}

// GRU elementwise
__global__ void gru_kernel(const float* __restrict__ G1, const float* __restrict__ G2,
                           const float* __restrict__ bx, const float* __restrict__ bh,
                           float* __restrict__ state, u16* __restrict__ GS) {
  const int b = blockIdx.x, d = threadIdx.x;
  const float* g1 = G1 + (size_t)b * 768;
  const float* g2 = G2 + (size_t)b * 768;
  float xz = g1[d] + bx[d], xr = g1[256 + d] + bx[256 + d], xh = g1[512 + d] + bx[512 + d];
  float hz = g2[d] + bh[d], hr = g2[256 + d] + bh[256 + d], hh2 = g2[512 + d] + bh[512 + d];
  float z = 1.f / (1.f + expf(-(xz + hz)));
  float r = 1.f / (1.f + expf(-(xr + hr)));
  float n = tanhf(xh + r * hh2);
  float h0 = state[b * 256 + d];
  float sn = z * h0 + (1.f - z) * n;
  state[b * 256 + d] = sn;
  GS[(size_t)b * 512 + 256 + d] = f2bf(sn);
}

extern "C" void kernel_launch(void* const* d_in, const int* in_sizes, int n_in,
                              void* d_out, int out_size, void* d_ws, size_t ws_size,
                              hipStream_t stream) {
  const float* nf  = (const float*)d_in[0];
  const float* Wg  = (const float*)d_in[2];
  const float* Ws  = (const float*)d_in[3];
  const float* asr = (const float*)d_in[4];
  const float* ads = (const float*)d_in[5];
  const float* wx  = (const float*)d_in[6];
  const float* wh  = (const float*)d_in[7];
  const float* bx  = (const float*)d_in[8];
  const float* bh  = (const float*)d_in[9];
  const float* pw  = (const float*)d_in[10];
  const float* pb  = (const float*)d_in[11];
  float* out = (float*)d_out;

  char* p = (char*)d_ws;
  size_t off = 0;
  auto alloc = [&](size_t bytes) { char* r = p + off; off += (bytes + 255) & ~255ULL; return r; };
  u16* W2T   = (u16*)alloc(512 * 256 * 2);   // row-major [N][K] (for HVSV GEMM)
  u16* BP    = (u16*)alloc(512 * 256 * 2);   // fragment-major (for fused_step)
  u16* WXT   = (u16*)alloc(768 * 256 * 2);
  u16* WHT   = (u16*)alloc(768 * 256 * 2);
  u16* PRJ   = (u16*)alloc(256 * 256 * 2);
  u16* X0    = (u16*)alloc((size_t)98304 * 256 * 2);
  u16* X1    = (u16*)alloc((size_t)98304 * 256 * 2);
  float* HVSV = (float*)alloc((size_t)2048 * 512 * 4);  // [hv | sv] per graph
  float* G1   = (float*)alloc((size_t)2048 * 768 * 4);
  float* G2   = (float*)alloc((size_t)2048 * 768 * 4);
  u16* GS     = (u16*)alloc((size_t)2048 * 512 * 2);    // [g0 | state] bf16
  float* ST   = (float*)alloc((size_t)2048 * 256 * 4);

  tcvt_all<<<2304, 256, 0, stream>>>(Wg, Ws, wx, wh, pw, W2T, WXT, WHT, PRJ);
  tcvt_bp<<<64, 256, 0, stream>>>(Wg, Ws, BP);
  prep_x_kernel<<<2048, 256, 0, stream>>>(nf, X0, ST, GS);

  u16* xc = X0; u16* xn = X1;
  for (int t = 0; t < 4; ++t) {
    // virtual row: hv = state@Wg, sv = state@Ws   (M=2048, N=512)
    gemm_bt<0><<<dim3(16, 4), 256, 0, stream>>>(GS + 256, 512, W2T, HVSV, 512, nullptr);
    // fused: h + attention + g0 + xnext (4 graphs/block)
    fused_step<<<512, 256, 0, stream>>>(xc, BP, HVSV, asr, ads, GS, (t < 3) ? xn : nullptr);
    // GRU gates (both in one launch)
    gemm_gates<<<dim3(16, 12), 256, 0, stream>>>(GS, WXT, WHT, G1, G2);
    gru_kernel<<<2048, 256, 0, stream>>>(G1, G2, bx, bh, ST, GS);
    u16* tmp = xc; xc = xn; xn = tmp;
  }
  // out = state @ proj_w + proj_b
  gemm_bt<2><<<dim3(16, 2), 256, 0, stream>>>(GS + 256, 512, PRJ, out, 256, pb);
}